// Round 14
// baseline (699.604 us; speedup 1.0000x reference)
//
#include <hip/hip_runtime.h>

#define N_HID 128
#define NS    512         // node slices; one aggregate block per slice
#define MAXNS 100         // max nodes/slice = ceil(50000/512)=98, padded
#define PBLK  128         // partition grid (scan handles NS*PBLK counts)

typedef short bf16x8 __attribute__((ext_vector_type(8)));
typedef float f32x4  __attribute__((ext_vector_type(4)));

// round-to-nearest-even f32 -> bf16 bits
static __device__ __forceinline__ unsigned short f2bf(float f)
{
    unsigned int u = __float_as_uint(f);
    u = (u + 0x7fffu + ((u >> 16) & 1u)) >> 16;
    return (unsigned short)u;
}
static __device__ __forceinline__ unsigned int pack2(float a, float b)
{
    return (unsigned int)f2bf(a) | ((unsigned int)f2bf(b) << 16);
}
static __device__ __forceinline__ float bf2f(unsigned int bits16)
{
    return __uint_as_float(bits16 << 16);
}
// exact integer slice map; MUST be identical in count/scatter/aggregate.
// d*NS fits 32-bit (50000*512 = 25.6M).
static __device__ __forceinline__ int slice_of(int d, int n)
{
    return (d * NS) / n;
}

// ---------------------------------------------------------------------------
// K1: blocks [0,PBLK) = per-block per-slice edge counts via LDS histogram.
// Blocks [PBLK,PBLK+16) = weight fragmentize (We 0-7, Ws 8-15).
// Blocks [PBLK+16,...) = cast h f32 -> hbf bf16 row-major.
// Frag layout per 16-row tile rt: [kc 0..3][lane 0..63][j 0..7] ushort,
// lane = ((k>>3)&3)*16 + (row&15), j = k&7.
// ---------------------------------------------------------------------------
__global__ __launch_bounds__(256) void count_fragw_cast(
    const int* __restrict__ dst, int* __restrict__ blockCnt, int E, int n,
    const float* __restrict__ We, const float* __restrict__ Ws,
    unsigned short* __restrict__ Be, unsigned short* __restrict__ Bs,
    const float* __restrict__ h, unsigned short* __restrict__ hbf, int total)
{
    int t = threadIdx.x, b = blockIdx.x;

    if (b >= PBLK + 16) {   // ---- cast h -> hbf ----
        int idx = (b - PBLK - 16) * 2048 + t * 8;
        if (idx + 8 <= total) {
            float4 v0 = *(const float4*)&h[idx];
            float4 v1 = *(const float4*)&h[idx + 4];
            uint4 pk;
            pk.x = pack2(v0.x, v0.y);
            pk.y = pack2(v0.z, v0.w);
            pk.z = pack2(v1.x, v1.y);
            pk.w = pack2(v1.z, v1.w);
            *(uint4*)&hbf[idx] = pk;
        }
        return;
    }

    if (b >= PBLK) {   // ---- weight fragmentize ----
        int bb = b - PBLK;
        const float* srcw = (bb < 8) ? We : Ws;
        unsigned short* dstF = (bb < 8) ? Be : Bs;
        int rt = bb & 7;
        int kc = t >> 6, l = t & 63, m = l & 15, q = l >> 4;
        const float* p = &srcw[(size_t)(rt * 16 + m) * N_HID + kc * 32 + q * 8];
        float4 v0 = *(const float4*)p;
        float4 v1 = *(const float4*)(p + 4);
        uint4 pk;
        pk.x = pack2(v0.x, v0.y);
        pk.y = pack2(v0.z, v0.w);
        pk.z = pack2(v1.x, v1.y);
        pk.w = pack2(v1.z, v1.w);
        *(uint4*)&dstF[(size_t)rt * 2048 + kc * 512 + l * 8] = pk;
        return;
    }

    // ---- edge slice counts (LDS histogram, 512 bins) ----
    __shared__ int hist[NS];
    hist[t] = 0; hist[t + 256] = 0;
    __syncthreads();
    for (int e = b * 256 + t; e < E; e += PBLK * 256)
        atomicAdd(&hist[slice_of(dst[e], n)], 1);
    __syncthreads();
    blockCnt[t * PBLK + b]         = hist[t];
    blockCnt[(t + 256) * PBLK + b] = hist[t + 256];
}

// ---------------------------------------------------------------------------
// K2: exclusive scan of NS*PBLK = 65536 counts (one block, 256 contiguous
// per thread) -> blockBase (same layout) + sbase[NS+1].
// ---------------------------------------------------------------------------
__global__ __launch_bounds__(256) void part_scan(
    const int* __restrict__ blockCnt, int* __restrict__ blockBase,
    int* __restrict__ sbase, int E)
{
    __shared__ int wsm[4];
    int t = threadIdx.x, lane = t & 63, wid = t >> 6;
    int base = t * 256;
    int s = 0;
    for (int i = 0; i < 256; ++i) s += blockCnt[base + i];
    int val = s;
#pragma unroll
    for (int off = 1; off < 64; off <<= 1) {
        int y = __shfl_up(val, off);
        if (lane >= off) val += y;
    }
    if (lane == 63) wsm[wid] = val;
    __syncthreads();
    if (t == 0) { int a = 0; for (int w = 0; w < 4; ++w) { int tmp = wsm[w]; wsm[w] = a; a += tmp; } }
    __syncthreads();
    int excl = wsm[wid] + val - s;
    for (int i = 0; i < 256; ++i) {
        int v = blockCnt[base + i];
        blockBase[base + i] = excl;
        excl += v;
    }
    __syncthreads();   // make blockBase stores visible block-wide
    sbase[t]       = blockBase[t * PBLK];
    sbase[t + 256] = blockBase[(t + 256) * PBLK];
    if (t == 0) sbase[NS] = E;
}

// ---------------------------------------------------------------------------
// K3: scatter edges into dense per-slice queues using precomputed
// per-(block,slice) bases — only LDS atomics. Packed u32 (d<<16)|s (n<=65536).
// ---------------------------------------------------------------------------
__global__ __launch_bounds__(256) void part_scatter(
    const int* __restrict__ src, const int* __restrict__ dst,
    const int* __restrict__ blockBase, unsigned int* __restrict__ part,
    int E, int n)
{
    __shared__ int cur[NS];
    int t = threadIdx.x, b = blockIdx.x;
    cur[t]       = blockBase[t * PBLK + b];
    cur[t + 256] = blockBase[(t + 256) * PBLK + b];
    __syncthreads();
    for (int e = b * 256 + t; e < E; e += PBLK * 256) {
        int d = dst[e], s = src[e];
        int sl  = slice_of(d, n);
        int pos = atomicAdd(&cur[sl], 1);
        part[pos] = ((unsigned int)d << 16) | (unsigned int)s;
    }
}

// ---------------------------------------------------------------------------
// K4: aggregate — one block per slice (~98 nodes). Full f32 accumulators in
// LDS (50KB, 2 blocks/CU); block scans its DENSE edge queue: 64 lanes read
// the hbf row (uint = 2 cols) and LDS-atomic-add. Degrees counted in LDS.
// No bucket, no CAP, no overflow. Epilogue: mean + write hagg in A-frag
// order: k=2l -> kc=l>>4, q=(l>>2)&3, j=(l&3)*2.
// ---------------------------------------------------------------------------
__global__ __launch_bounds__(256) void aggregate(
    const unsigned int* __restrict__ part,
    const int* __restrict__ sbase,
    const unsigned short* __restrict__ hbf,
    unsigned short* __restrict__ hagg,
    int n)
{
    __shared__ float acc[MAXNS * N_HID];   // 50 KB
    __shared__ int   degs[MAXNS];

    int t = threadIdx.x;
    int s = blockIdx.x;
    int lo_node = (s * n + NS - 1) / NS;           // first node owned
    int hi_node = ((s + 1) * n + NS - 1) / NS;     // first node of next slice
    int ns = hi_node - lo_node;                    // <= 98

    for (int i = t; i < MAXNS * N_HID; i += 256) acc[i] = 0.f;
    for (int i = t; i < MAXNS; i += 256) degs[i] = 0;
    __syncthreads();

    int lane = t & 63, w = t >> 6;
    int e0 = sbase[s], e1 = sbase[s + 1];
    int nEdges = e1 - e0;
    const unsigned int* h32 = (const unsigned int*)hbf;   // 64 uints per row

    for (int c0 = w * 64; c0 < nEdges; c0 += 256) {
        int rem = nEdges - c0;
        int nv  = rem < 64 ? rem : 64;
        unsigned int pk = (lane < nv) ? part[e0 + c0 + lane] : 0u;

        int j = 0;
        for (; j + 8 <= nv; j += 8) {
            unsigned int vv[8]; int dl[8];
#pragma unroll
            for (int k = 0; k < 8; ++k) {
                unsigned int pkj = __shfl(pk, j + k);
                dl[k] = (int)(pkj >> 16) - lo_node;
                vv[k] = h32[(size_t)(pkj & 0xffffu) * 64 + lane];
            }
#pragma unroll
            for (int k = 0; k < 8; ++k) {
                atomicAdd(&acc[dl[k] * N_HID + 2 * lane],     bf2f(vv[k] & 0xffffu));
                atomicAdd(&acc[dl[k] * N_HID + 2 * lane + 1], bf2f(vv[k] >> 16));
                if (lane == 0) atomicAdd(&degs[dl[k]], 1);
            }
        }
        for (; j < nv; ++j) {
            unsigned int pkj = __shfl(pk, j);
            int dl = (int)(pkj >> 16) - lo_node;
            unsigned int v = h32[(size_t)(pkj & 0xffffu) * 64 + lane];
            atomicAdd(&acc[dl * N_HID + 2 * lane],     bf2f(v & 0xffffu));
            atomicAdd(&acc[dl * N_HID + 2 * lane + 1], bf2f(v >> 16));
            if (lane == 0) atomicAdd(&degs[dl], 1);
        }
    }
    __syncthreads();

    // epilogue: mean + hagg write in A-frag order (disjoint uints per node)
    for (int i = w; i < ns; i += 4) {
        int dg = degs[i];
        float sc = dg > 0 ? 1.0f / (float)dg : 0.f;
        float a0 = acc[i * N_HID + 2 * lane] * sc;
        float a1 = acc[i * N_HID + 2 * lane + 1] * sc;
        int node = lo_node + i;
        int rt = node >> 4, mm = node & 15;
        int kc = lane >> 4, q = (lane >> 2) & 3, jj = (lane & 3) * 2;
        *(unsigned int*)&hagg[(size_t)rt * 2048 + kc * 512 + (q * 16 + mm) * 8 + jj]
            = pack2(a0, a1);
    }
}

// ---------------------------------------------------------------------------
// K5: final fused GEMM, no LDS. One wave per 16-row tile.
// out = relu(hbf·Ws^T + b + hagg·We^T). hbf A-frags load as permuted-
// contiguous tiles from row-major; hagg/B frags lane-linear.
// D layout: col = lane&15, row = (lane>>4)*4 + reg.
// ---------------------------------------------------------------------------
__global__ __launch_bounds__(256) void gemm_final(
    const unsigned short* __restrict__ hbf,
    const unsigned short* __restrict__ hagg,
    const unsigned short* __restrict__ Be,
    const unsigned short* __restrict__ Bsf,
    const float* __restrict__ bias,
    float* __restrict__ out,
    int n, int nrt)
{
    int w = (int)((blockIdx.x * blockDim.x + threadIdx.x) >> 6);
    if (w >= nrt) return;
    int l = threadIdx.x & 63;
    int m = l & 15, q = l >> 4;
    int row0 = w * 16;

    bf16x8 ah[4];
#pragma unroll
    for (int kc = 0; kc < 4; ++kc) {
        int gr = row0 + m; if (gr > n - 1) gr = n - 1;
        ah[kc] = *(const bf16x8*)&hbf[(size_t)gr * N_HID + kc * 32 + q * 8];
    }
    const bf16x8* Gp = (const bf16x8*)(hagg + (size_t)w * 2048);
    bf16x8 ag0 = Gp[l], ag1 = Gp[64 + l], ag2 = Gp[128 + l], ag3 = Gp[192 + l];

    const int colb = l & 15;
    const int rq   = (l >> 4) * 4;

#pragma unroll
    for (int ct = 0; ct < 8; ++ct) {
        const bf16x8* BpS = (const bf16x8*)(Bsf + (size_t)ct * 2048);
        const bf16x8* BpE = (const bf16x8*)(Be  + (size_t)ct * 2048);
        f32x4 acc = {0.f, 0.f, 0.f, 0.f};
        acc = __builtin_amdgcn_mfma_f32_16x16x32_bf16(ah[0], BpS[l],       acc, 0, 0, 0);
        acc = __builtin_amdgcn_mfma_f32_16x16x32_bf16(ah[1], BpS[64 + l],  acc, 0, 0, 0);
        acc = __builtin_amdgcn_mfma_f32_16x16x32_bf16(ah[2], BpS[128 + l], acc, 0, 0, 0);
        acc = __builtin_amdgcn_mfma_f32_16x16x32_bf16(ah[3], BpS[192 + l], acc, 0, 0, 0);
        acc = __builtin_amdgcn_mfma_f32_16x16x32_bf16(ag0,   BpE[l],       acc, 0, 0, 0);
        acc = __builtin_amdgcn_mfma_f32_16x16x32_bf16(ag1,   BpE[64 + l],  acc, 0, 0, 0);
        acc = __builtin_amdgcn_mfma_f32_16x16x32_bf16(ag2,   BpE[128 + l], acc, 0, 0, 0);
        acc = __builtin_amdgcn_mfma_f32_16x16x32_bf16(ag3,   BpE[192 + l], acc, 0, 0, 0);

        int col = ct * 16 + colb;
        float bv = bias[col];
#pragma unroll
        for (int r = 0; r < 4; ++r) {
            int row = row0 + rq + r;
            if (row < n) out[(size_t)row * N_HID + col] = fmaxf(acc[r] + bv, 0.f);
        }
    }
}

// ---------------------------------------------------------------------------
extern "C" void kernel_launch(void* const* d_in, const int* in_sizes, int n_in,
                              void* d_out, int out_size, void* d_ws, size_t ws_size,
                              hipStream_t stream)
{
    const float* h   = (const float*)d_in[0];
    const int*   src = (const int*)d_in[1];
    const int*   dst = (const int*)d_in[2];
    const float* We  = (const float*)d_in[3];
    const float* Ws  = (const float*)d_in[4];
    const float* bs  = (const float*)d_in[5];
    float*       out = (float*)d_out;

    const int n   = in_sizes[0] / N_HID;    // 50000
    const int E   = in_sizes[1];            // 800000
    const int nrt = (n + 15) / 16;          // 3125 row tiles
    const int total = n * N_HID;

    // workspace (~30 MB of the 256 MiB d_ws)
    unsigned short* hbf  = (unsigned short*)d_ws;             // n*128 bf16 row-major (12.8 MB)
    unsigned short* hagg = hbf + (size_t)n * N_HID;           // nrt*2048 frag order  (12.8 MB)
    unsigned short* Be   = hagg + (size_t)nrt * 2048;         // 8*2048
    unsigned short* Bs   = Be + 8 * 2048;                     // 8*2048
    int* blockCnt  = (int*)(Bs + 8 * 2048);                   // NS*PBLK (256 KB)
    int* blockBase = blockCnt + NS * PBLK;                    // NS*PBLK (256 KB)
    int* sbase     = blockBase + NS * PBLK;                   // NS+1 (+pad)
    unsigned int* part = (unsigned int*)(sbase + NS + 16);    // E u32 (3.2 MB)

    const int castBlocks = (total + 2047) / 2048;             // 3125

    count_fragw_cast<<<PBLK + 16 + castBlocks, 256, 0, stream>>>(
        dst, blockCnt, E, n, We, Ws, Be, Bs, h, hbf, total);
    part_scan<<<1, 256, 0, stream>>>(blockCnt, blockBase, sbase, E);
    part_scatter<<<PBLK, 256, 0, stream>>>(src, dst, blockBase, part, E, n);
    aggregate<<<NS, 256, 0, stream>>>(part, sbase, hbf, hagg, n);
    gemm_final<<<(nrt + 3) / 4, 256, 0, stream>>>(hbf, hagg, Be, Bs, bs, out, n, nrt);
}